// Round 19
// baseline (165.831 us; speedup 1.0000x reference)
//
#include <hip/hip_runtime.h>
#include <hip/hip_bf16.h>

#define HH 256   // hidden dim
#define HJ 128   // H/2
#define GG 512   // number of graphs

typedef __attribute__((ext_vector_type(8))) short short8;
typedef __attribute__((ext_vector_type(4))) float f32x4;

static __device__ __forceinline__ unsigned f2bfu(float f) {
  // round-to-nearest-even fp32 -> bf16 (inputs finite), as low 16 bits
  unsigned u = __builtin_bit_cast(unsigned, f);
  return (u + 0x7FFFu + ((u >> 16) & 1u)) >> 16;
}

static __device__ __forceinline__ uint2 pack4(const float4 f) {
  return make_uint2(f2bfu(f.x) | (f2bfu(f.y) << 16),
                    f2bfu(f.z) | (f2bfu(f.w) << 16));
}

// ---------------- Kernel 0: pre-fragment W1^T into MFMA A-operand order ----
// w1a[kt*8+jt][lane] = 8 bf16: A[m=j][k] with j = jt*16+(l&15), k = kt*32+(l>>4)*8+i
__global__ __launch_bounds__(64) void w1frag_kernel(
    const float* __restrict__ W1, short8* __restrict__ w1a) {
  const int l = threadIdx.x;
  const int kt = blockIdx.x >> 3;
  const int jt = blockIdx.x & 7;
  const int j = jt * 16 + (l & 15);
  const int kb = kt * 32 + (l >> 4) * 8;
  short8 v;
#pragma unroll
  for (int i = 0; i < 8; ++i) v[i] = (short)f2bfu(W1[(size_t)(kb + i) * HJ + j]);
  w1a[blockIdx.x * 64 + l] = v;
}

// ---------------- segment offsets from sorted batch ----------------
__global__ __launch_bounds__(256) void segstart_kernel(
    const int* __restrict__ batch, int* __restrict__ segstart, int N, int G) {
  const int n = blockIdx.x * 256 + threadIdx.x;
  if (n >= N) return;
  const int b = batch[n];
  const int p = (n == 0) ? -1 : batch[n - 1];
  for (int g = p + 1; g <= b; ++g) segstart[g] = n;
  if (n == N - 1) {
    for (int g = b + 1; g <= G; ++g) segstart[g] = N;
  }
}

// ---------------- Fused kernel: one 768-thread block per graph -------------
// Waves 0-3 (gate): j-tiles w,w+4; MFMA tile i + tanh epilogue -> spart[i&1].
// Waves 4-7 (sweep): combine e(i-1), channel-sweep tile i-1.
// Waves 8-11 (stage): load+pack+write tile i+1.
// 3 LDS tile buffers (64x256 bf16, XOR-swizzled); 1 barrier/iter.
// 12 waves/CU = 3 waves/SIMD (VGPR cap 170 -- gate fits).
__global__ __launch_bounds__(768, 1) void fused_kernel(
    const float* __restrict__ x, const short8* __restrict__ w1a,
    const float* __restrict__ b1, const float* __restrict__ W2,
    const int* __restrict__ segstart, const float* __restrict__ Wp,
    const float* __restrict__ bp, float4* __restrict__ out4, int N) {
  __shared__ char xb[3 * 32768];     // 96 KB: 3 bf16 x-tiles [64][256] swizzled
  __shared__ float spart[2][8][64];  // 4 KB: per-j-tile partial s, dbuf
  __shared__ float elds[64];
  __shared__ float esums;

  const int tid = threadIdx.x;
  const int l = tid & 63;
  const int w = tid >> 6;  // wave 0..11
  const int g = blockIdx.x;

  const int n0 = segstart[g];
  const int n1 = segstart[g + 1];
  const int cnt = n1 - n0;
  if (cnt <= 0) return;  // block-uniform, before any barrier

  const int ntiles = (cnt + 63) >> 6;
  const float4* x4 = (const float4*)x;

  // gate waves: A-frags + b1/W2 for j-tiles jt0 and jt0+4
  const int jt0 = w & 3;
  short8 afrag[2][8];
  float4 bb[2], ww[2];
  if (w < 4) {
#pragma unroll
    for (int jj = 0; jj < 2; ++jj) {
      const int jt = jt0 + jj * 4;
#pragma unroll
      for (int kt = 0; kt < 8; ++kt) afrag[jj][kt] = w1a[(kt * 8 + jt) * 64 + l];
      const int j0 = 16 * jt + (l >> 4) * 4;
      bb[jj] = *reinterpret_cast<const float4*>(b1 + j0);
      ww[jj] = *reinterpret_cast<const float4*>(W2 + j0);
    }
  }

  // prologue: waves 0-7 stage tile 0 (wave w: rows w*8..w*8+7, 1KB bursts)
  if (w < 8) {
    float4 rr[8];
#pragma unroll
    for (int k = 0; k < 8; ++k) {
      const int node = min(n0 + w * 8 + k, N - 1);
      rr[k] = x4[(size_t)node * 64 + l];
    }
#pragma unroll
    for (int k = 0; k < 8; ++k) {
      const int r = w * 8 + k;
      const int swz = (r & 7) << 4;
      *reinterpret_cast<uint2*>(xb + r * 512 + ((l * 8) ^ swz)) = pack4(rr[k]);
    }
  }
  __syncthreads();

  // sweep mapping (valid for w in 4..7): channel pair + node half
  const int pid = tid - 256;
  const int c2 = pid & 127;
  const int qh = (pid >> 7) & 1;
  float2 pacc = make_float2(0.f, 0.f);
  float es_acc = 0.f;

  for (int i = 0; i < ntiles; ++i) {
    if (w < 4) {
      // ---- gate: MFMA tile i -> spart[i&1] ----
      const char* xbi = xb + (i % 3) * 32768;
      float* sp = &spart[i & 1][0][0];
#pragma unroll
      for (int nt = 0; nt < 4; ++nt) {
        const int node = nt * 16 + (l & 15);
        const int nb = node * 512;
        const int swz = (node & 7) << 4;
        short8 bfrag[8];
#pragma unroll
        for (int kt = 0; kt < 8; ++kt) {
          bfrag[kt] = *reinterpret_cast<const short8*>(
              xbi + nb + ((kt * 64 + ((l >> 4) << 4)) ^ swz));
        }
#pragma unroll
        for (int jj = 0; jj < 2; ++jj) {
          f32x4 acc = (f32x4)(0.f);
#pragma unroll
          for (int kt = 0; kt < 8; ++kt) {
            acc = __builtin_amdgcn_mfma_f32_16x16x32_bf16(afrag[jj][kt],
                                                          bfrag[kt], acc, 0, 0, 0);
          }
          float t0 = __expf(2.f * (acc[0] + bb[jj].x));
          float t1 = __expf(2.f * (acc[1] + bb[jj].y));
          float t2 = __expf(2.f * (acc[2] + bb[jj].z));
          float t3 = __expf(2.f * (acc[3] + bb[jj].w));
          float ps = (1.f - 2.f / (t0 + 1.f)) * ww[jj].x +
                     (1.f - 2.f / (t1 + 1.f)) * ww[jj].y +
                     (1.f - 2.f / (t2 + 1.f)) * ww[jj].z +
                     (1.f - 2.f / (t3 + 1.f)) * ww[jj].w;
          ps += __shfl_xor(ps, 16, 64);
          ps += __shfl_xor(ps, 32, 64);
          if (l < 16) sp[(jt0 + jj * 4) * 64 + node] = ps;
        }
      }
    } else if (w < 8) {
      // ---- sweep: combine e(i-1) + channel-sweep tile i-1 ----
      if (i >= 1) {
        const float* sp = &spart[(i - 1) & 1][0][0];
        float s = 0.f;
#pragma unroll
        for (int jt = 0; jt < 8; ++jt) s += sp[jt * 64 + l];
        const int node = n0 + (i - 1) * 64 + l;
        const float e = (node < n1) ? __expf(s) : 0.f;
        elds[l] = e;  // all 4 sweep waves write identical values
        if (w == 4) es_acc += e;
        const char* xbs = xb + ((i - 1) % 3) * 32768;
#pragma unroll 8
        for (int m = 0; m < 32; ++m) {
          const int n = qh * 32 + m;
          const unsigned v = *reinterpret_cast<const unsigned*>(
              xbs + n * 512 + ((c2 * 4) ^ ((n & 7) << 4)));
          const float ee = elds[n];
          pacc.x = fmaf(__builtin_bit_cast(float, v << 16), ee, pacc.x);
          pacc.y = fmaf(__builtin_bit_cast(float, v & 0xFFFF0000u), ee, pacc.y);
        }
      }
    } else {
      // ---- stage: load+pack+write tile i+1 (wave w: 16 rows) ----
      if (i + 1 < ntiles) {
        char* xbd = xb + ((i + 1) % 3) * 32768;
        const int rb = (w - 8) * 16;
        float4 rr[8];
#pragma unroll
        for (int b = 0; b < 2; ++b) {
#pragma unroll
          for (int k = 0; k < 8; ++k) {
            const int node = min(n0 + (i + 1) * 64 + rb + b * 8 + k, N - 1);
            rr[k] = x4[(size_t)node * 64 + l];
          }
#pragma unroll
          for (int k = 0; k < 8; ++k) {
            const int r = rb + b * 8 + k;
            const int swz = (r & 7) << 4;
            *reinterpret_cast<uint2*>(xbd + r * 512 + ((l * 8) ^ swz)) =
                pack4(rr[k]);
          }
        }
      }
    }
    __syncthreads();
  }

  // drain: combine + sweep the last tile (sweep waves)
  if (w >= 4 && w < 8) {
    const float* sp = &spart[(ntiles - 1) & 1][0][0];
    float s = 0.f;
#pragma unroll
    for (int jt = 0; jt < 8; ++jt) s += sp[jt * 64 + l];
    const int node = n0 + (ntiles - 1) * 64 + l;
    const float e = (node < n1) ? __expf(s) : 0.f;
    elds[l] = e;
    if (w == 4) es_acc += e;
    const char* xbs = xb + ((ntiles - 1) % 3) * 32768;
#pragma unroll 8
    for (int m = 0; m < 32; ++m) {
      const int n = qh * 32 + m;
      const unsigned v = *reinterpret_cast<const unsigned*>(
          xbs + n * 512 + ((c2 * 4) ^ ((n & 7) << 4)));
      const float ee = elds[n];
      pacc.x = fmaf(__builtin_bit_cast(float, v << 16), ee, pacc.x);
      pacc.y = fmaf(__builtin_bit_cast(float, v & 0xFFFF0000u), ee, pacc.y);
    }
    if (w == 4) {
      float es = es_acc;
      es += __shfl_xor(es, 1, 64);
      es += __shfl_xor(es, 2, 64);
      es += __shfl_xor(es, 4, 64);
      es += __shfl_xor(es, 8, 64);
      es += __shfl_xor(es, 16, 64);
      es += __shfl_xor(es, 32, 64);
      if (l == 0) esums = es;
    }
  }
  __syncthreads();

  // ---- pooled partials -> emb -> proj -> broadcast (xb reused as float) ----
  float* fbase = (float*)xb;  // qredf [2][256] at 0; er at +512; pr at +768
  if (w >= 4 && w < 8) {
    fbase[qh * 256 + c2 * 2] = pacc.x;
    fbase[qh * 256 + c2 * 2 + 1] = pacc.y;
  }
  __syncthreads();

  float* er = fbase + 512;
  if (tid < HH) {
    const float es = esums;
    const float inv = (es > 0.f) ? 1.f / es : 0.f;
    er[tid] = (fbase[tid] + fbase[256 + tid]) * inv;
  }
  __syncthreads();

  float* pr = fbase + 768;
  if (tid < 512) {
    const int c = tid & 255;
    const int h2 = tid >> 8;
    float p = 0.f;
    const float* wp = Wp + (size_t)h2 * 128 * HH + c;
#pragma unroll 4
    for (int k = 0; k < 128; ++k) {
      p = fmaf(er[h2 * 128 + k], wp[(size_t)k * HH], p);
    }
    pr[h2 * 256 + c] = p;
  }
  __syncthreads();
  float* ctxl = fbase + 1280;
  if (tid < HH) {
    ctxl[tid] = pr[tid] + pr[256 + tid] + bp[tid];
  }
  __syncthreads();

  // broadcast ctx row to all nodes of the graph (coalesced 1KB/wave rows)
  {
    const int q = tid & 63;
    const float4 cv = reinterpret_cast<const float4*>(ctxl)[q];
    for (int n = n0 + w; n < n1; n += 12) {
      out4[(size_t)n * 64 + q] = cv;
    }
  }
}

extern "C" void kernel_launch(void* const* d_in, const int* in_sizes, int n_in,
                              void* d_out, int out_size, void* d_ws, size_t ws_size,
                              hipStream_t stream) {
  const float* x = (const float*)d_in[0];
  const int* batch = (const int*)d_in[1];
  const float* W1 = (const float*)d_in[2];
  const float* b1 = (const float*)d_in[3];
  const float* W2 = (const float*)d_in[4];
  // d_in[5] = b2 (unused: softmax shift-invariant)
  const float* Wp = (const float*)d_in[6];
  const float* bp = (const float*)d_in[7];
  float* out = (float*)d_out;

  const int N = in_sizes[1];
  const int G = GG;

  // workspace layout (16B aligned)
  char* wsp = (char*)d_ws;
  short8* w1a = (short8*)wsp;           // 4096 short8 = 64 KB
  size_t off = 4096 * sizeof(short8);
  int* segstart = (int*)(wsp + off);    // G+1 ints

  // fragment W1
  w1frag_kernel<<<dim3(64), 64, 0, stream>>>(W1, w1a);
  // segment offsets
  {
    dim3 grid((N + 255) / 256);
    segstart_kernel<<<grid, 256, 0, stream>>>(batch, segstart, N, G);
  }
  // fused gate + pool + project + broadcast (3 specialist wave groups)
  fused_kernel<<<dim3(G), 768, 0, stream>>>(x, w1a, b1, W2, segstart, Wp, bp,
                                            (float4*)out, N);
}

// Round 20
// 115.108 us; speedup vs baseline: 1.4406x; 1.4406x over previous
//
#include <hip/hip_runtime.h>
#include <hip/hip_bf16.h>

#define HH 256   // hidden dim
#define HJ 128   // H/2
#define GG 512   // number of graphs

typedef __attribute__((ext_vector_type(8))) short short8;
typedef __attribute__((ext_vector_type(4))) float f32x4;

static __device__ __forceinline__ unsigned f2bfu(float f) {
  // round-to-nearest-even fp32 -> bf16 (inputs finite), as low 16 bits
  unsigned u = __builtin_bit_cast(unsigned, f);
  return (u + 0x7FFFu + ((u >> 16) & 1u)) >> 16;
}

static __device__ __forceinline__ uint2 pack4(const float4 f) {
  return make_uint2(f2bfu(f.x) | (f2bfu(f.y) << 16),
                    f2bfu(f.z) | (f2bfu(f.w) << 16));
}

// fast tanh via exp + v_rcp_f32 (~1e-7 rel err; absmax headroom is 13x)
static __device__ __forceinline__ float fast_tanh_pos2e(float e2h) {
  // e2h = exp(2h); tanh(h) = 1 - 2/(e2h+1)
  return 1.f - 2.f * __builtin_amdgcn_rcpf(e2h + 1.f);
}

// ---------------- Kernel 0: pre-fragment W1^T into MFMA A-operand order ----
// w1a[kt*8+jt][lane] = 8 bf16: A[m=j][k] with j = jt*16+(l&15), k = kt*32+(l>>4)*8+i
__global__ __launch_bounds__(64) void w1frag_kernel(
    const float* __restrict__ W1, short8* __restrict__ w1a) {
  const int l = threadIdx.x;
  const int kt = blockIdx.x >> 3;
  const int jt = blockIdx.x & 7;
  const int j = jt * 16 + (l & 15);
  const int kb = kt * 32 + (l >> 4) * 8;
  short8 v;
#pragma unroll
  for (int i = 0; i < 8; ++i) v[i] = (short)f2bfu(W1[(size_t)(kb + i) * HJ + j]);
  w1a[blockIdx.x * 64 + l] = v;
}

// ---------------- segment offsets from sorted batch ----------------
__global__ __launch_bounds__(256) void segstart_kernel(
    const int* __restrict__ batch, int* __restrict__ segstart, int N, int G) {
  const int n = blockIdx.x * 256 + threadIdx.x;
  if (n >= N) return;
  const int b = batch[n];
  const int p = (n == 0) ? -1 : batch[n - 1];
  for (int g = p + 1; g <= b; ++g) segstart[g] = n;
  if (n == N - 1) {
    for (int g = b + 1; g <= G; ++g) segstart[g] = N;
  }
}

// ---------------- Fused kernel: one block per graph, wave-specialized ------
// Waves 0-3 (gate): MFMA tile i + tanh epilogue -> spart[i&1].
// Waves 4-7 (pool): combine e(i-1), sweep tile i-1, stage tile i+1.
// 3 LDS tile buffers (64 nodes x 256 ch bf16, XOR-swizzled); 1 barrier/iter.
__global__ __launch_bounds__(512) void fused_kernel(
    const float* __restrict__ x, const short8* __restrict__ w1a,
    const float* __restrict__ b1, const float* __restrict__ W2,
    const int* __restrict__ segstart, const float* __restrict__ Wp,
    const float* __restrict__ bp, float4* __restrict__ out4, int N) {
  __shared__ char xb[3 * 32768];     // 96 KB: 3 bf16 x-tiles [64][256] swizzled
  __shared__ float spart[2][8][64];  // 4 KB: per-j-tile partial s, dbuf
  __shared__ float elds[64];
  __shared__ float esums;

  const int tid = threadIdx.x;
  const int l = tid & 63;
  const int w = tid >> 6;  // wave 0..7
  const int g = blockIdx.x;

  const int n0 = segstart[g];
  const int n1 = segstart[g + 1];
  const int cnt = n1 - n0;
  if (cnt <= 0) return;  // block-uniform, before any barrier

  const int ntiles = (cnt + 63) >> 6;
  const float4* x4 = (const float4*)x;

  // gate waves: A-frags + b1/W2 for j-tiles jt0 and jt0+4
  const int jt0 = w & 3;
  short8 afrag[2][8];
  float4 bb[2], ww[2];
  if (w < 4) {
#pragma unroll
    for (int jj = 0; jj < 2; ++jj) {
      const int jt = jt0 + jj * 4;
#pragma unroll
      for (int kt = 0; kt < 8; ++kt) afrag[jj][kt] = w1a[(kt * 8 + jt) * 64 + l];
      const int j0 = 16 * jt + (l >> 4) * 4;
      bb[jj] = *reinterpret_cast<const float4*>(b1 + j0);
      ww[jj] = *reinterpret_cast<const float4*>(W2 + j0);
    }
  }

  // prologue: all 8 waves stage tile 0 (wave w: rows w*8..w*8+7, 1KB bursts)
  {
    float4 rr[8];
#pragma unroll
    for (int k = 0; k < 8; ++k) {
      const int node = min(n0 + w * 8 + k, N - 1);
      rr[k] = x4[(size_t)node * 64 + l];
    }
#pragma unroll
    for (int k = 0; k < 8; ++k) {
      const int r = w * 8 + k;
      const int swz = (r & 7) << 4;
      *reinterpret_cast<uint2*>(xb + r * 512 + ((l * 8) ^ swz)) = pack4(rr[k]);
    }
  }
  __syncthreads();

  const int c2 = tid & 127;        // pool sweep: channel pair
  const int qh = (tid >> 7) & 1;   // pool sweep: node half
  float2 pacc = make_float2(0.f, 0.f);
  float es_acc = 0.f;

  for (int i = 0; i < ntiles; ++i) {
    if (w < 4) {
      // ---- gate: MFMA tile i -> spart[i&1] ----
      const char* xbi = xb + (i % 3) * 32768;
      float* sp = &spart[i & 1][0][0];
#pragma unroll
      for (int nt = 0; nt < 4; ++nt) {
        const int node = nt * 16 + (l & 15);
        const int nb = node * 512;
        const int swz = (node & 7) << 4;
        short8 bfrag[8];
#pragma unroll
        for (int kt = 0; kt < 8; ++kt) {
          bfrag[kt] = *reinterpret_cast<const short8*>(
              xbi + nb + ((kt * 64 + ((l >> 4) << 4)) ^ swz));
        }
#pragma unroll
        for (int jj = 0; jj < 2; ++jj) {
          f32x4 acc = (f32x4)(0.f);
#pragma unroll
          for (int kt = 0; kt < 8; ++kt) {
            acc = __builtin_amdgcn_mfma_f32_16x16x32_bf16(afrag[jj][kt],
                                                          bfrag[kt], acc, 0, 0, 0);
          }
          float t0 = __expf(2.f * (acc[0] + bb[jj].x));
          float t1 = __expf(2.f * (acc[1] + bb[jj].y));
          float t2 = __expf(2.f * (acc[2] + bb[jj].z));
          float t3 = __expf(2.f * (acc[3] + bb[jj].w));
          float ps = fast_tanh_pos2e(t0) * ww[jj].x +
                     fast_tanh_pos2e(t1) * ww[jj].y +
                     fast_tanh_pos2e(t2) * ww[jj].z +
                     fast_tanh_pos2e(t3) * ww[jj].w;
          ps += __shfl_xor(ps, 16, 64);
          ps += __shfl_xor(ps, 32, 64);
          if (l < 16) sp[(jt0 + jj * 4) * 64 + node] = ps;
        }
      }
    } else {
      // ---- pool: combine e(i-1) + sweep tile i-1, then stage tile i+1 ----
      if (i >= 1) {
        const float* sp = &spart[(i - 1) & 1][0][0];
        float s = 0.f;
#pragma unroll
        for (int jt = 0; jt < 8; ++jt) s += sp[jt * 64 + l];
        const int node = n0 + (i - 1) * 64 + l;
        const float e = (node < n1) ? __expf(s) : 0.f;
        elds[l] = e;  // all 4 pool waves write identical values
        if (w == 4) es_acc += e;
        const char* xbs = xb + ((i - 1) % 3) * 32768;
#pragma unroll 8
        for (int m = 0; m < 32; ++m) {
          const int n = qh * 32 + m;
          const unsigned v = *reinterpret_cast<const unsigned*>(
              xbs + n * 512 + ((c2 * 4) ^ ((n & 7) << 4)));
          const float ee = elds[n];
          pacc.x = fmaf(__builtin_bit_cast(float, v << 16), ee, pacc.x);
          pacc.y = fmaf(__builtin_bit_cast(float, v & 0xFFFF0000u), ee, pacc.y);
        }
      }
      if (i + 1 < ntiles) {
        char* xbd = xb + ((i + 1) % 3) * 32768;
        const int rb = (w - 4) * 16;
        float4 rr[8];
#pragma unroll
        for (int b = 0; b < 2; ++b) {
#pragma unroll
          for (int k = 0; k < 8; ++k) {
            const int node = min(n0 + (i + 1) * 64 + rb + b * 8 + k, N - 1);
            rr[k] = x4[(size_t)node * 64 + l];
          }
#pragma unroll
          for (int k = 0; k < 8; ++k) {
            const int r = rb + b * 8 + k;
            const int swz = (r & 7) << 4;
            *reinterpret_cast<uint2*>(xbd + r * 512 + ((l * 8) ^ swz)) =
                pack4(rr[k]);
          }
        }
      }
    }
    __syncthreads();
  }

  // drain: combine + sweep the last tile (pool waves)
  if (w >= 4) {
    const float* sp = &spart[(ntiles - 1) & 1][0][0];
    float s = 0.f;
#pragma unroll
    for (int jt = 0; jt < 8; ++jt) s += sp[jt * 64 + l];
    const int node = n0 + (ntiles - 1) * 64 + l;
    const float e = (node < n1) ? __expf(s) : 0.f;
    elds[l] = e;
    if (w == 4) es_acc += e;
    const char* xbs = xb + ((ntiles - 1) % 3) * 32768;
#pragma unroll 8
    for (int m = 0; m < 32; ++m) {
      const int n = qh * 32 + m;
      const unsigned v = *reinterpret_cast<const unsigned*>(
          xbs + n * 512 + ((c2 * 4) ^ ((n & 7) << 4)));
      const float ee = elds[n];
      pacc.x = fmaf(__builtin_bit_cast(float, v << 16), ee, pacc.x);
      pacc.y = fmaf(__builtin_bit_cast(float, v & 0xFFFF0000u), ee, pacc.y);
    }
    if (w == 4) {
      float es = es_acc;
      es += __shfl_xor(es, 1, 64);
      es += __shfl_xor(es, 2, 64);
      es += __shfl_xor(es, 4, 64);
      es += __shfl_xor(es, 8, 64);
      es += __shfl_xor(es, 16, 64);
      es += __shfl_xor(es, 32, 64);
      if (l == 0) esums = es;
    }
  }
  __syncthreads();

  // ---- pooled partials -> emb -> proj -> broadcast (xb reused as float) ----
  float* fbase = (float*)xb;  // qredf [2][256] at 0; er at +512; pr at +768
  if (w >= 4) {
    fbase[qh * 256 + c2 * 2] = pacc.x;
    fbase[qh * 256 + c2 * 2 + 1] = pacc.y;
  }
  __syncthreads();

  float* er = fbase + 512;
  if (tid < HH) {
    const float es = esums;
    const float inv = (es > 0.f) ? 1.f / es : 0.f;
    er[tid] = (fbase[tid] + fbase[256 + tid]) * inv;
  }
  __syncthreads();

  float* pr = fbase + 768;
  {
    const int c = tid & 255;
    const int h2 = tid >> 8;
    float p = 0.f;
    const float* wp = Wp + (size_t)h2 * 128 * HH + c;
#pragma unroll 4
    for (int k = 0; k < 128; ++k) {
      p = fmaf(er[h2 * 128 + k], wp[(size_t)k * HH], p);
    }
    pr[h2 * 256 + c] = p;
  }
  __syncthreads();
  float* ctxl = fbase + 1280;
  if (tid < HH) {
    ctxl[tid] = pr[tid] + pr[256 + tid] + bp[tid];
  }
  __syncthreads();

  // broadcast ctx row to all nodes of the graph (coalesced 1KB/wave rows)
  {
    const int q = tid & 63;
    const float4 cv = reinterpret_cast<const float4*>(ctxl)[q];
    for (int n = n0 + w; n < n1; n += 8) {
      out4[(size_t)n * 64 + q] = cv;
    }
  }
}

extern "C" void kernel_launch(void* const* d_in, const int* in_sizes, int n_in,
                              void* d_out, int out_size, void* d_ws, size_t ws_size,
                              hipStream_t stream) {
  const float* x = (const float*)d_in[0];
  const int* batch = (const int*)d_in[1];
  const float* W1 = (const float*)d_in[2];
  const float* b1 = (const float*)d_in[3];
  const float* W2 = (const float*)d_in[4];
  // d_in[5] = b2 (unused: softmax shift-invariant)
  const float* Wp = (const float*)d_in[6];
  const float* bp = (const float*)d_in[7];
  float* out = (float*)d_out;

  const int N = in_sizes[1];
  const int G = GG;

  // workspace layout (16B aligned)
  char* wsp = (char*)d_ws;
  short8* w1a = (short8*)wsp;           // 4096 short8 = 64 KB
  size_t off = 4096 * sizeof(short8);
  int* segstart = (int*)(wsp + off);    // G+1 ints

  // fragment W1
  w1frag_kernel<<<dim3(64), 64, 0, stream>>>(W1, w1a);
  // segment offsets
  {
    dim3 grid((N + 255) / 256);
    segstart_kernel<<<grid, 256, 0, stream>>>(batch, segstart, N, G);
  }
  // fused gate + pool + project + broadcast (wave-specialized)
  fused_kernel<<<dim3(G), 512, 0, stream>>>(x, w1a, b1, W2, segstart, Wp, bp,
                                            (float4*)out, N);
}

// Round 22
// 104.836 us; speedup vs baseline: 1.5818x; 1.0980x over previous
//
#include <hip/hip_runtime.h>
#include <hip/hip_bf16.h>

#define HH 256   // hidden dim
#define HJ 128   // H/2
#define GG 512   // number of graphs

typedef __attribute__((ext_vector_type(8))) short short8;
typedef __attribute__((ext_vector_type(4))) float f32x4;

static __device__ __forceinline__ unsigned f2bfu(float f) {
  // round-to-nearest-even fp32 -> bf16 (inputs finite), as low 16 bits
  unsigned u = __builtin_bit_cast(unsigned, f);
  return (u + 0x7FFFu + ((u >> 16) & 1u)) >> 16;
}

static __device__ __forceinline__ uint2 pack4(const float4 f) {
  return make_uint2(f2bfu(f.x) | (f2bfu(f.y) << 16),
                    f2bfu(f.z) | (f2bfu(f.w) << 16));
}

// fast tanh via exp + v_rcp_f32 (~1e-7 rel err; absmax headroom is 13x)
static __device__ __forceinline__ float fast_tanh_pos2e(float e2h) {
  // e2h = exp(2h); tanh(h) = 1 - 2/(e2h+1)
  return 1.f - 2.f * __builtin_amdgcn_rcpf(e2h + 1.f);
}

// ---------------- Kernel 0: pre-fragment W1^T into MFMA A-operand order ----
// w1a[kt*8+jt][lane] = 8 bf16: A[m=j][k] with j = jt*16+(l&15), k = kt*32+(l>>4)*8+i
__global__ __launch_bounds__(64) void w1frag_kernel(
    const float* __restrict__ W1, short8* __restrict__ w1a) {
  const int l = threadIdx.x;
  const int kt = blockIdx.x >> 3;
  const int jt = blockIdx.x & 7;
  const int j = jt * 16 + (l & 15);
  const int kb = kt * 32 + (l >> 4) * 8;
  short8 v;
#pragma unroll
  for (int i = 0; i < 8; ++i) v[i] = (short)f2bfu(W1[(size_t)(kb + i) * HJ + j]);
  w1a[blockIdx.x * 64 + l] = v;
}

// ---------------- segment offsets from sorted batch ----------------
__global__ __launch_bounds__(256) void segstart_kernel(
    const int* __restrict__ batch, int* __restrict__ segstart, int N, int G) {
  const int n = blockIdx.x * 256 + threadIdx.x;
  if (n >= N) return;
  const int b = batch[n];
  const int p = (n == 0) ? -1 : batch[n - 1];
  for (int g = p + 1; g <= b; ++g) segstart[g] = n;
  if (n == N - 1) {
    for (int g = b + 1; g <= G; ++g) segstart[g] = N;
  }
}

// ---------------- Fused kernel: one block per graph, wave-specialized ------
// Waves 0-3 (gate): MFMA tile i + tanh epilogue -> spart[i&1].
// Waves 4-7 (pool): combine e(i-1), sweep tile i-1, stage tile i+1.
// 3 LDS tile buffers (64 nodes x 256 ch bf16, XOR-swizzled); 1 barrier/iter.
// Output broadcast uses NON-TEMPORAL stores so the 200 MB write stream does
// not evict x from L3 (replay FETCH showed 111 MB of avoidable HBM re-read).
__global__ __launch_bounds__(512) void fused_kernel(
    const float* __restrict__ x, const short8* __restrict__ w1a,
    const float* __restrict__ b1, const float* __restrict__ W2,
    const int* __restrict__ segstart, const float* __restrict__ Wp,
    const float* __restrict__ bp, f32x4* __restrict__ out4, int N) {
  __shared__ char xb[3 * 32768];     // 96 KB: 3 bf16 x-tiles [64][256] swizzled
  __shared__ float spart[2][8][64];  // 4 KB: per-j-tile partial s, dbuf
  __shared__ float elds[64];
  __shared__ float esums;

  const int tid = threadIdx.x;
  const int l = tid & 63;
  const int w = tid >> 6;  // wave 0..7
  const int g = blockIdx.x;

  const int n0 = segstart[g];
  const int n1 = segstart[g + 1];
  const int cnt = n1 - n0;
  if (cnt <= 0) return;  // block-uniform, before any barrier

  const int ntiles = (cnt + 63) >> 6;
  const float4* x4 = (const float4*)x;

  // gate waves: A-frags + b1/W2 for j-tiles jt0 and jt0+4
  const int jt0 = w & 3;
  short8 afrag[2][8];
  float4 bb[2], ww[2];
  if (w < 4) {
#pragma unroll
    for (int jj = 0; jj < 2; ++jj) {
      const int jt = jt0 + jj * 4;
#pragma unroll
      for (int kt = 0; kt < 8; ++kt) afrag[jj][kt] = w1a[(kt * 8 + jt) * 64 + l];
      const int j0 = 16 * jt + (l >> 4) * 4;
      bb[jj] = *reinterpret_cast<const float4*>(b1 + j0);
      ww[jj] = *reinterpret_cast<const float4*>(W2 + j0);
    }
  }

  // prologue: all 8 waves stage tile 0 (wave w: rows w*8..w*8+7, 1KB bursts)
  {
    float4 rr[8];
#pragma unroll
    for (int k = 0; k < 8; ++k) {
      const int node = min(n0 + w * 8 + k, N - 1);
      rr[k] = x4[(size_t)node * 64 + l];
    }
#pragma unroll
    for (int k = 0; k < 8; ++k) {
      const int r = w * 8 + k;
      const int swz = (r & 7) << 4;
      *reinterpret_cast<uint2*>(xb + r * 512 + ((l * 8) ^ swz)) = pack4(rr[k]);
    }
  }
  __syncthreads();

  const int c2 = tid & 127;        // pool sweep: channel pair
  const int qh = (tid >> 7) & 1;   // pool sweep: node half
  float2 pacc = make_float2(0.f, 0.f);
  float es_acc = 0.f;

  for (int i = 0; i < ntiles; ++i) {
    if (w < 4) {
      // ---- gate: MFMA tile i -> spart[i&1] ----
      const char* xbi = xb + (i % 3) * 32768;
      float* sp = &spart[i & 1][0][0];
#pragma unroll
      for (int nt = 0; nt < 4; ++nt) {
        const int node = nt * 16 + (l & 15);
        const int nb = node * 512;
        const int swz = (node & 7) << 4;
        short8 bfrag[8];
#pragma unroll
        for (int kt = 0; kt < 8; ++kt) {
          bfrag[kt] = *reinterpret_cast<const short8*>(
              xbi + nb + ((kt * 64 + ((l >> 4) << 4)) ^ swz));
        }
#pragma unroll
        for (int jj = 0; jj < 2; ++jj) {
          f32x4 acc = (f32x4)(0.f);
#pragma unroll
          for (int kt = 0; kt < 8; ++kt) {
            acc = __builtin_amdgcn_mfma_f32_16x16x32_bf16(afrag[jj][kt],
                                                          bfrag[kt], acc, 0, 0, 0);
          }
          float t0 = __expf(2.f * (acc[0] + bb[jj].x));
          float t1 = __expf(2.f * (acc[1] + bb[jj].y));
          float t2 = __expf(2.f * (acc[2] + bb[jj].z));
          float t3 = __expf(2.f * (acc[3] + bb[jj].w));
          float ps = fast_tanh_pos2e(t0) * ww[jj].x +
                     fast_tanh_pos2e(t1) * ww[jj].y +
                     fast_tanh_pos2e(t2) * ww[jj].z +
                     fast_tanh_pos2e(t3) * ww[jj].w;
          ps += __shfl_xor(ps, 16, 64);
          ps += __shfl_xor(ps, 32, 64);
          if (l < 16) sp[(jt0 + jj * 4) * 64 + node] = ps;
        }
      }
    } else {
      // ---- pool: combine e(i-1) + sweep tile i-1, then stage tile i+1 ----
      if (i >= 1) {
        const float* sp = &spart[(i - 1) & 1][0][0];
        float s = 0.f;
#pragma unroll
        for (int jt = 0; jt < 8; ++jt) s += sp[jt * 64 + l];
        const int node = n0 + (i - 1) * 64 + l;
        const float e = (node < n1) ? __expf(s) : 0.f;
        elds[l] = e;  // all 4 pool waves write identical values
        if (w == 4) es_acc += e;
        const char* xbs = xb + ((i - 1) % 3) * 32768;
#pragma unroll 8
        for (int m = 0; m < 32; ++m) {
          const int n = qh * 32 + m;
          const unsigned v = *reinterpret_cast<const unsigned*>(
              xbs + n * 512 + ((c2 * 4) ^ ((n & 7) << 4)));
          const float ee = elds[n];
          pacc.x = fmaf(__builtin_bit_cast(float, v << 16), ee, pacc.x);
          pacc.y = fmaf(__builtin_bit_cast(float, v & 0xFFFF0000u), ee, pacc.y);
        }
      }
      if (i + 1 < ntiles) {
        char* xbd = xb + ((i + 1) % 3) * 32768;
        const int rb = (w - 4) * 16;
        float4 rr[8];
#pragma unroll
        for (int b = 0; b < 2; ++b) {
#pragma unroll
          for (int k = 0; k < 8; ++k) {
            const int node = min(n0 + (i + 1) * 64 + rb + b * 8 + k, N - 1);
            rr[k] = x4[(size_t)node * 64 + l];
          }
#pragma unroll
          for (int k = 0; k < 8; ++k) {
            const int r = rb + b * 8 + k;
            const int swz = (r & 7) << 4;
            *reinterpret_cast<uint2*>(xbd + r * 512 + ((l * 8) ^ swz)) =
                pack4(rr[k]);
          }
        }
      }
    }
    __syncthreads();
  }

  // drain: combine + sweep the last tile (pool waves)
  if (w >= 4) {
    const float* sp = &spart[(ntiles - 1) & 1][0][0];
    float s = 0.f;
#pragma unroll
    for (int jt = 0; jt < 8; ++jt) s += sp[jt * 64 + l];
    const int node = n0 + (ntiles - 1) * 64 + l;
    const float e = (node < n1) ? __expf(s) : 0.f;
    elds[l] = e;
    if (w == 4) es_acc += e;
    const char* xbs = xb + ((ntiles - 1) % 3) * 32768;
#pragma unroll 8
    for (int m = 0; m < 32; ++m) {
      const int n = qh * 32 + m;
      const unsigned v = *reinterpret_cast<const unsigned*>(
          xbs + n * 512 + ((c2 * 4) ^ ((n & 7) << 4)));
      const float ee = elds[n];
      pacc.x = fmaf(__builtin_bit_cast(float, v << 16), ee, pacc.x);
      pacc.y = fmaf(__builtin_bit_cast(float, v & 0xFFFF0000u), ee, pacc.y);
    }
    if (w == 4) {
      float es = es_acc;
      es += __shfl_xor(es, 1, 64);
      es += __shfl_xor(es, 2, 64);
      es += __shfl_xor(es, 4, 64);
      es += __shfl_xor(es, 8, 64);
      es += __shfl_xor(es, 16, 64);
      es += __shfl_xor(es, 32, 64);
      if (l == 0) esums = es;
    }
  }
  __syncthreads();

  // ---- pooled partials -> emb -> proj -> broadcast (xb reused as float) ----
  float* fbase = (float*)xb;  // qredf [2][256] at 0; er at +512; pr at +768
  if (w >= 4) {
    fbase[qh * 256 + c2 * 2] = pacc.x;
    fbase[qh * 256 + c2 * 2 + 1] = pacc.y;
  }
  __syncthreads();

  float* er = fbase + 512;
  if (tid < HH) {
    const float es = esums;
    const float inv = (es > 0.f) ? 1.f / es : 0.f;
    er[tid] = (fbase[tid] + fbase[256 + tid]) * inv;
  }
  __syncthreads();

  float* pr = fbase + 768;
  {
    const int c = tid & 255;
    const int h2 = tid >> 8;
    float p = 0.f;
    const float* wp = Wp + (size_t)h2 * 128 * HH + c;
#pragma unroll 4
    for (int k = 0; k < 128; ++k) {
      p = fmaf(er[h2 * 128 + k], wp[(size_t)k * HH], p);
    }
    pr[h2 * 256 + c] = p;
  }
  __syncthreads();
  float* ctxl = fbase + 1280;
  if (tid < HH) {
    ctxl[tid] = pr[tid] + pr[256 + tid] + bp[tid];
  }
  __syncthreads();

  // broadcast ctx row to all nodes of the graph (coalesced 1KB/wave rows)
  // NON-TEMPORAL: out is write-only; keep it from evicting x in L2/L3.
  {
    const int q = tid & 63;
    const f32x4 cv = reinterpret_cast<const f32x4*>(ctxl)[q];
    for (int n = n0 + w; n < n1; n += 8) {
      __builtin_nontemporal_store(cv, &out4[(size_t)n * 64 + q]);
    }
  }
}

extern "C" void kernel_launch(void* const* d_in, const int* in_sizes, int n_in,
                              void* d_out, int out_size, void* d_ws, size_t ws_size,
                              hipStream_t stream) {
  const float* x = (const float*)d_in[0];
  const int* batch = (const int*)d_in[1];
  const float* W1 = (const float*)d_in[2];
  const float* b1 = (const float*)d_in[3];
  const float* W2 = (const float*)d_in[4];
  // d_in[5] = b2 (unused: softmax shift-invariant)
  const float* Wp = (const float*)d_in[6];
  const float* bp = (const float*)d_in[7];
  float* out = (float*)d_out;

  const int N = in_sizes[1];
  const int G = GG;

  // workspace layout (16B aligned)
  char* wsp = (char*)d_ws;
  short8* w1a = (short8*)wsp;           // 4096 short8 = 64 KB
  size_t off = 4096 * sizeof(short8);
  int* segstart = (int*)(wsp + off);    // G+1 ints

  // fragment W1
  w1frag_kernel<<<dim3(64), 64, 0, stream>>>(W1, w1a);
  // segment offsets
  {
    dim3 grid((N + 255) / 256);
    segstart_kernel<<<grid, 256, 0, stream>>>(batch, segstart, N, G);
  }
  // fused gate + pool + project + broadcast (wave-specialized, NT stores)
  fused_kernel<<<dim3(G), 512, 0, stream>>>(x, w1a, b1, W2, segstart, Wp, bp,
                                            (f32x4*)out, N);
}

// Round 23
// 94.413 us; speedup vs baseline: 1.7564x; 1.1104x over previous
//
#include <hip/hip_runtime.h>
#include <hip/hip_bf16.h>

#define HH 256   // hidden dim
#define HJ 128   // H/2
#define GG 512   // number of graphs

typedef __attribute__((ext_vector_type(8))) short short8;
typedef __attribute__((ext_vector_type(4))) float f32x4;

static __device__ __forceinline__ unsigned f2bfu(float f) {
  // round-to-nearest-even fp32 -> bf16 (inputs finite), as low 16 bits
  unsigned u = __builtin_bit_cast(unsigned, f);
  return (u + 0x7FFFu + ((u >> 16) & 1u)) >> 16;
}

static __device__ __forceinline__ uint2 pack4(const float4 f) {
  return make_uint2(f2bfu(f.x) | (f2bfu(f.y) << 16),
                    f2bfu(f.z) | (f2bfu(f.w) << 16));
}

// fast tanh via exp + v_rcp_f32 (~1e-7 rel err; absmax headroom is 13x)
static __device__ __forceinline__ float fast_tanh_pos2e(float e2h) {
  return 1.f - 2.f * __builtin_amdgcn_rcpf(e2h + 1.f);
}

// ---------------- Kernel 0: pre-fragment W1^T into MFMA A-operand order ----
__global__ __launch_bounds__(64) void w1frag_kernel(
    const float* __restrict__ W1, short8* __restrict__ w1a) {
  const int l = threadIdx.x;
  const int kt = blockIdx.x >> 3;
  const int jt = blockIdx.x & 7;
  const int j = jt * 16 + (l & 15);
  const int kb = kt * 32 + (l >> 4) * 8;
  short8 v;
#pragma unroll
  for (int i = 0; i < 8; ++i) v[i] = (short)f2bfu(W1[(size_t)(kb + i) * HJ + j]);
  w1a[blockIdx.x * 64 + l] = v;
}

// ---------------- segment offsets from sorted batch ----------------
__global__ __launch_bounds__(256) void segstart_kernel(
    const int* __restrict__ batch, int* __restrict__ segstart, int N, int G) {
  const int n = blockIdx.x * 256 + threadIdx.x;
  if (n >= N) return;
  const int b = batch[n];
  const int p = (n == 0) ? -1 : batch[n - 1];
  for (int g = p + 1; g <= b; ++g) segstart[g] = n;
  if (n == N - 1) {
    for (int g = b + 1; g <= G; ++g) segstart[g] = N;
  }
}

// ---------------- Fused kernel: TWO graphs per block -----------------------
// Per graph: waves 0-3 gate (MFMA+tanh -> spart), waves 4-7 pool (combine e,
// sweep, stage). While graph 1 computes, graph 0's output rows are dribbled
// out by pool waves (NT stores) and the leftover by gate waves in the drain,
// hiding the per-block write tail under the next graph's compute loop.
__global__ __launch_bounds__(512) void fused_kernel(
    const float* __restrict__ x, const short8* __restrict__ w1a,
    const float* __restrict__ b1, const float* __restrict__ W2,
    const int* __restrict__ segstart, const float* __restrict__ Wp,
    const float* __restrict__ bp, f32x4* __restrict__ out4, int N) {
  __shared__ char xb[3 * 32768];     // 96 KB: 3 bf16 x-tiles [64][256] swizzled
  __shared__ float spart[2][8][64];  // 4 KB
  __shared__ float elds[64];
  __shared__ float esums;
  __shared__ float ctxp[HH];         // previous graph's ctx row (1 KB)

  const int tid = threadIdx.x;
  const int l = tid & 63;
  const int w = tid >> 6;  // wave 0..7
  const float4* x4 = (const float4*)x;

  // gate waves: A-frags + b1/W2 for j-tiles jt0 and jt0+4 (same both graphs)
  const int jt0 = w & 3;
  short8 afrag[2][8];
  float4 bb[2], ww[2];
  if (w < 4) {
#pragma unroll
    for (int jj = 0; jj < 2; ++jj) {
      const int jt = jt0 + jj * 4;
#pragma unroll
      for (int kt = 0; kt < 8; ++kt) afrag[jj][kt] = w1a[(kt * 8 + jt) * 64 + l];
      const int j0 = 16 * jt + (l >> 4) * 4;
      bb[jj] = *reinterpret_cast<const float4*>(b1 + j0);
      ww[jj] = *reinterpret_cast<const float4*>(W2 + j0);
    }
  }

  const int c2 = tid & 127;        // pool sweep: channel pair
  const int qh = (tid >> 7) & 1;   // pool sweep: node half

  int pn0 = 0, pn1 = 0;
  bool pvalid = false;

  for (int gi = 0; gi < 2; ++gi) {
    const int g = blockIdx.x * 2 + gi;
    const int n0 = segstart[g];
    const int n1 = segstart[g + 1];
    const int cnt = n1 - n0;
    if (cnt <= 0) continue;  // block-uniform

    const int ntiles = (cnt + 63) >> 6;

    // prologue: all 8 waves stage tile 0
    {
      float4 rr[8];
#pragma unroll
      for (int k = 0; k < 8; ++k) {
        const int node = min(n0 + w * 8 + k, N - 1);
        rr[k] = x4[(size_t)node * 64 + l];
      }
#pragma unroll
      for (int k = 0; k < 8; ++k) {
        const int r = w * 8 + k;
        const int swz = (r & 7) << 4;
        *reinterpret_cast<uint2*>(xb + r * 512 + ((l * 8) ^ swz)) = pack4(rr[k]);
      }
    }
    __syncthreads();

    // previous graph's ctx fragment for the dribble writes
    f32x4 cvp;
    if (pvalid) cvp = reinterpret_cast<const f32x4*>(ctxp)[l];

    float2 pacc = make_float2(0.f, 0.f);
    float es_acc = 0.f;

    for (int i = 0; i < ntiles; ++i) {
      if (w < 4) {
        // ---- gate: MFMA tile i -> spart[i&1] ----
        const char* xbi = xb + (i % 3) * 32768;
        float* sp = &spart[i & 1][0][0];
#pragma unroll
        for (int nt = 0; nt < 4; ++nt) {
          const int node = nt * 16 + (l & 15);
          const int nb = node * 512;
          const int swz = (node & 7) << 4;
          short8 bfrag[8];
#pragma unroll
          for (int kt = 0; kt < 8; ++kt) {
            bfrag[kt] = *reinterpret_cast<const short8*>(
                xbi + nb + ((kt * 64 + ((l >> 4) << 4)) ^ swz));
          }
#pragma unroll
          for (int jj = 0; jj < 2; ++jj) {
            f32x4 acc = (f32x4)(0.f);
#pragma unroll
            for (int kt = 0; kt < 8; ++kt) {
              acc = __builtin_amdgcn_mfma_f32_16x16x32_bf16(afrag[jj][kt],
                                                            bfrag[kt], acc, 0, 0, 0);
            }
            float t0 = __expf(2.f * (acc[0] + bb[jj].x));
            float t1 = __expf(2.f * (acc[1] + bb[jj].y));
            float t2 = __expf(2.f * (acc[2] + bb[jj].z));
            float t3 = __expf(2.f * (acc[3] + bb[jj].w));
            float ps = fast_tanh_pos2e(t0) * ww[jj].x +
                       fast_tanh_pos2e(t1) * ww[jj].y +
                       fast_tanh_pos2e(t2) * ww[jj].z +
                       fast_tanh_pos2e(t3) * ww[jj].w;
            ps += __shfl_xor(ps, 16, 64);
            ps += __shfl_xor(ps, 32, 64);
            if (l < 16) sp[(jt0 + jj * 4) * 64 + node] = ps;
          }
        }
      } else {
        // ---- pool: combine e(i-1) + sweep tile i-1, stage tile i+1 ----
        if (i >= 1) {
          const float* sp = &spart[(i - 1) & 1][0][0];
          float s = 0.f;
#pragma unroll
          for (int jt = 0; jt < 8; ++jt) s += sp[jt * 64 + l];
          const int node = n0 + (i - 1) * 64 + l;
          const float e = (node < n1) ? __expf(s) : 0.f;
          elds[l] = e;
          if (w == 4) es_acc += e;
          const char* xbs = xb + ((i - 1) % 3) * 32768;
#pragma unroll 8
          for (int m = 0; m < 32; ++m) {
            const int n = qh * 32 + m;
            const unsigned v = *reinterpret_cast<const unsigned*>(
                xbs + n * 512 + ((c2 * 4) ^ ((n & 7) << 4)));
            const float ee = elds[n];
            pacc.x = fmaf(__builtin_bit_cast(float, v << 16), ee, pacc.x);
            pacc.y = fmaf(__builtin_bit_cast(float, v & 0xFFFF0000u), ee, pacc.y);
          }
        }
        if (i + 1 < ntiles) {
          char* xbd = xb + ((i + 1) % 3) * 32768;
          const int rb = (w - 4) * 16;
          float4 rr[8];
#pragma unroll
          for (int b = 0; b < 2; ++b) {
#pragma unroll
            for (int k = 0; k < 8; ++k) {
              const int node = min(n0 + (i + 1) * 64 + rb + b * 8 + k, N - 1);
              rr[k] = x4[(size_t)node * 64 + l];
            }
#pragma unroll
            for (int k = 0; k < 8; ++k) {
              const int r = rb + b * 8 + k;
              const int swz = (r & 7) << 4;
              *reinterpret_cast<uint2*>(xbd + r * 512 + ((l * 8) ^ swz)) =
                  pack4(rr[k]);
            }
          }
        }
        // ---- dribble previous graph's output rows (NT, fire-and-forget) --
        if (pvalid) {
          const int rbase = i * 64 + (w - 4) * 16;
#pragma unroll 4
          for (int k = 0; k < 16; ++k) {
            const int n = pn0 + rbase + k;
            if (n < pn1) {
              __builtin_nontemporal_store(cvp, &out4[(size_t)n * 64 + l]);
            }
          }
        }
      }
      __syncthreads();
    }

    // drain: pool waves finish last tile; gate waves write prev leftover
    if (w >= 4) {
      const float* sp = &spart[(ntiles - 1) & 1][0][0];
      float s = 0.f;
#pragma unroll
      for (int jt = 0; jt < 8; ++jt) s += sp[jt * 64 + l];
      const int node = n0 + (ntiles - 1) * 64 + l;
      const float e = (node < n1) ? __expf(s) : 0.f;
      elds[l] = e;
      if (w == 4) es_acc += e;
      const char* xbs = xb + ((ntiles - 1) % 3) * 32768;
#pragma unroll 8
      for (int m = 0; m < 32; ++m) {
        const int n = qh * 32 + m;
        const unsigned v = *reinterpret_cast<const unsigned*>(
            xbs + n * 512 + ((c2 * 4) ^ ((n & 7) << 4)));
        const float ee = elds[n];
        pacc.x = fmaf(__builtin_bit_cast(float, v << 16), ee, pacc.x);
        pacc.y = fmaf(__builtin_bit_cast(float, v & 0xFFFF0000u), ee, pacc.y);
      }
      if (w == 4) {
        float es = es_acc;
        es += __shfl_xor(es, 1, 64);
        es += __shfl_xor(es, 2, 64);
        es += __shfl_xor(es, 4, 64);
        es += __shfl_xor(es, 8, 64);
        es += __shfl_xor(es, 16, 64);
        es += __shfl_xor(es, 32, 64);
        if (l == 0) esums = es;
      }
    } else if (pvalid) {
      // leftover rows of prev graph not covered by the dribble
      const f32x4 cvl = reinterpret_cast<const f32x4*>(ctxp)[l];
      for (int n = pn0 + ntiles * 64 + w; n < pn1; n += 4) {
        __builtin_nontemporal_store(cvl, &out4[(size_t)n * 64 + l]);
      }
    }
    __syncthreads();

    // ---- pooled partials -> emb -> proj -> ctx (xb reused as float) ----
    float* fbase = (float*)xb;
    if (w >= 4) {
      fbase[qh * 256 + c2 * 2] = pacc.x;
      fbase[qh * 256 + c2 * 2 + 1] = pacc.y;
    }
    __syncthreads();

    float* er = fbase + 512;
    if (tid < HH) {
      const float es = esums;
      const float inv = (es > 0.f) ? 1.f / es : 0.f;
      er[tid] = (fbase[tid] + fbase[256 + tid]) * inv;
    }
    __syncthreads();

    float* pr = fbase + 768;
    {
      const int c = tid & 255;
      const int h2 = tid >> 8;
      float p = 0.f;
      const float* wp = Wp + (size_t)h2 * 128 * HH + c;
#pragma unroll 4
      for (int k = 0; k < 128; ++k) {
        p = fmaf(er[h2 * 128 + k], wp[(size_t)k * HH], p);
      }
      pr[h2 * 256 + c] = p;
    }
    __syncthreads();
    if (tid < HH) {
      ctxp[tid] = pr[tid] + pr[256 + tid] + bp[tid];
    }
    pn0 = n0;
    pn1 = n1;
    pvalid = true;
    __syncthreads();  // ctxp stable before next graph's staging reuses xb
  }

  // final: write the last processed graph's rows (exposed tail)
  if (pvalid) {
    const f32x4 cv = reinterpret_cast<const f32x4*>(ctxp)[l];
    for (int n = pn0 + w; n < pn1; n += 8) {
      __builtin_nontemporal_store(cv, &out4[(size_t)n * 64 + l]);
    }
  }
}

extern "C" void kernel_launch(void* const* d_in, const int* in_sizes, int n_in,
                              void* d_out, int out_size, void* d_ws, size_t ws_size,
                              hipStream_t stream) {
  const float* x = (const float*)d_in[0];
  const int* batch = (const int*)d_in[1];
  const float* W1 = (const float*)d_in[2];
  const float* b1 = (const float*)d_in[3];
  const float* W2 = (const float*)d_in[4];
  // d_in[5] = b2 (unused: softmax shift-invariant)
  const float* Wp = (const float*)d_in[6];
  const float* bp = (const float*)d_in[7];
  float* out = (float*)d_out;

  const int N = in_sizes[1];
  const int G = GG;

  // workspace layout (16B aligned)
  char* wsp = (char*)d_ws;
  short8* w1a = (short8*)wsp;           // 4096 short8 = 64 KB
  size_t off = 4096 * sizeof(short8);
  int* segstart = (int*)(wsp + off);    // G+1 ints

  // fragment W1
  w1frag_kernel<<<dim3(64), 64, 0, stream>>>(W1, w1a);
  // segment offsets
  {
    dim3 grid((N + 255) / 256);
    segstart_kernel<<<grid, 256, 0, stream>>>(batch, segstart, N, G);
  }
  // fused: 2 graphs per block, write tail of graph k hidden under graph k+1
  fused_kernel<<<dim3(G / 2), 512, 0, stream>>>(x, w1a, b1, W2, segstart, Wp,
                                                bp, (f32x4*)out, N);
}